// Round 12
// baseline (283.980 us; speedup 1.0000x reference)
//
#include <hip/hip_runtime.h>
#include <math.h>

#define N_NODES 50000
#define FIN 512
#define NE 800000
#define ETOT 850000   // NE + N_NODES self loops
#define F1 128        // H1*C1
#define H1 8
#define F2 40
#define BCAP 64       // bucket capacity per node (deg ~ 1+Poisson(16), P(>64) ~ 1e-20)
#define NBIN 391      // coarse bins of 128 nodes (ceil(50000/128))
#define BINCAP 3072   // per-bin edge capacity (mean 2176, sd 47 -> 19 sd margin)

typedef __attribute__((ext_vector_type(8))) short bf16x8;
typedef __attribute__((ext_vector_type(4))) float f32x4;

__device__ inline ushort f2bf(float f){
  union{float f; unsigned u;} v; v.f=f;
  return (ushort)((v.u + 0x8000u) >> 16);
}
__device__ inline float bflo(uint u){ union{uint a;float f;} v; v.a = u << 16;         return v.f; }
__device__ inline float bfhi(uint u){ union{uint a;float f;} v; v.a = u & 0xffff0000u; return v.f; }
__device__ inline float bf1(ushort u){ union{uint a;float f;} v; v.a = ((uint)u) << 16; return v.f; }

__device__ inline bf16x8 cvt8(float4 a, float4 b){
  union{ushort u[8]; bf16x8 v;} r;
  r.u[0]=f2bf(a.x); r.u[1]=f2bf(a.y); r.u[2]=f2bf(a.z); r.u[3]=f2bf(a.w);
  r.u[4]=f2bf(b.x); r.u[5]=f2bf(b.y); r.u[6]=f2bf(b.z); r.u[7]=f2bf(b.w);
  return r.v;
}

// ---------------- k_pro: role-split merge of binA (blocks 0..103) + W-convert (blocks 104..173) -------
// binA bins edges into 391 ranges of 128 nodes (LDS histogram, chunked writes).

__global__ __launch_bounds__(1024) void k_pro(const int* __restrict__ src, const int* __restrict__ dst,
                                              int* __restrict__ binCursor, uint* __restrict__ binbuf,
                                              const float* __restrict__ W1, const float* __restrict__ W2,
                                              ushort* __restrict__ Wtb, ushort* __restrict__ Wt2){
  __shared__ int hist[512];
  __shared__ int base[512];
  int bx = blockIdx.x, t = threadIdx.x;

  if(bx < 104){
    if(t < 512) hist[t] = 0;
    __syncthreads();

    uint pk[8]; int bn[8];
    int i0 = bx*8192 + t;
    #pragma unroll
    for(int k=0;k<8;k++){
      int i = i0 + k*1024;
      int d = -1, s = 0;
      if(i < NE){ d = dst[i]; s = src[i]; }
      else if(i < ETOT){ d = i - NE; s = d; }
      if(d >= 0){
        bn[k] = d >> 7;
        pk[k] = ((uint)d << 16) | (uint)s;
        atomicAdd(&hist[bn[k]], 1);
      } else bn[k] = -1;
    }
    __syncthreads();
    if(t < 512){
      int h = hist[t];
      base[t] = (t < NBIN && h > 0) ? atomicAdd(&binCursor[t], h) : 0;
    }
    __syncthreads();
    if(t < 512) hist[t] = 0;   // reuse as local cursor
    __syncthreads();
    #pragma unroll
    for(int k=0;k<8;k++){
      if(bn[k] >= 0){
        int off = atomicAdd(&hist[bn[k]], 1);
        binbuf[(size_t)bn[k]*BINCAP + base[bn[k]] + off] = pk[k];
      }
    }
  } else {
    // ---- W1 + W2 convert to frag-blocked layouts ----
    int id = (bx - 104)*1024 + t;            // 0..71679
    if(id < 65536){
      int k = id >> 7, n = id & 127;
      Wtb[(size_t)(k>>3)*1024 + n*8 + (k&7)] = f2bf(W1[id]);
    } else {
      int id2 = id - 65536;
      if(id2 < 6144){
        int j = id2 & 7;
        int tt = id2 >> 3;         // 768
        int n = tt % 48;
        int t2 = tt / 48;          // 16
        int quad = t2 & 3, ks = t2 >> 2;
        int k = ks*32 + quad*8 + j;
        Wt2[id2] = (n < F2) ? f2bf(W2[k*F2 + n]) : (ushort)0;
      }
    }
  }
}

// ---------------- k_g1b: role-split at 256 threads — binB (blocks 0..390) + GEMM1 (blocks 391..1953) --
// GEMM1: DMA-staged A (R11, verified) upgraded to a 3-buffer pipeline with COUNTED vmcnt (T3/T4):
// stage tile t+2 at iter t; end-of-iter wait = vmcnt(6) (leaves this iter's 2 DMA + 4 B-loads in
// flight; tile t+1's DMA, issued last iter, is older -> complete), vmcnt(4) on the tail iter,
// vmcnt(0) once in prologue. sched_barrier(0) pins issue order around the wait (rule #18);
// unroll 1 keeps per-iter barriers. This stops draining the just-issued prefetch (the R6-R11
// ~58us plateau: MfmaUtil 4%, HBM 16%, everything waiting on memory at the barrier).

__global__ __launch_bounds__(256) void k_g1b(const int* __restrict__ binCursor, const uint* __restrict__ binbuf,
                                             int* __restrict__ cnt, ushort* __restrict__ bucket,
                                             const float* __restrict__ x, const ushort* __restrict__ Wtb,
                                             const float* __restrict__ as_w, const float* __restrict__ ad_w,
                                             ushort* __restrict__ h1b,
                                             float* __restrict__ a_src, float* __restrict__ a_dst){
  __shared__ __align__(16) char smem[24576];   // gemm: 3 x 8KB A-buffers; binB: 17408 B
  int bxg = blockIdx.x;

  if(bxg < NBIN){
    // ---- binB: per-128-node-bin LDS bucket build, coalesced writeout ----
    int* lcnt  = (int*)smem;                  // 128 ints
    ushort* lb = (ushort*)(smem + 512);       // [128][66] (pad 66: scatter banks spread by dl)
    int b = bxg, t = threadIdx.x;
    if(t < 128) lcnt[t] = 0;
    __syncthreads();
    int m = min(binCursor[b], BINCAP);
    const uint* p = binbuf + (size_t)b*BINCAP;
    for(int i=t; i<m; i+=256){
      uint pk = p[i];
      int dl = (pk >> 16) & 127;
      int pos = atomicAdd(&lcnt[dl], 1);
      if(pos < BCAP) lb[dl*66 + pos] = (ushort)(pk & 0xFFFF);
    }
    __syncthreads();
    int n0 = b << 7;
    int nrows = min(128, N_NODES - n0);
    if(t < nrows) cnt[n0 + t] = lcnt[t];
    const uint* s4 = (const uint*)(smem + 512);
    uint* d4 = (uint*)(bucket + ((size_t)n0 << 6));
    int total = nrows * 32;        // 32 dwords (64 ushorts) per row
    for(int i=t; i<total; i+=256){
      int r = i >> 5, c = i & 31;
      d4[i] = s4[r*33 + c];
    }
    return;
  }

  // ---- GEMM1 (bf16 MFMA), 32 rows/block, 3-deep DMA pipeline, + fused att-score epilogue ----
  float* AsmF = (float*)smem;                 // [3][32][64] fp32 (8 KB per buffer)
  int tid = threadIdx.x;
  int bx  = bxg - NBIN;                       // 0..1562
  int wave = tid >> 6, lane = tid & 63;
  int l15 = lane & 15, quad = lane >> 4;

  f32x4 acc[2][2];
  #pragma unroll
  for(int i=0;i<2;i++)
    #pragma unroll
    for(int j=0;j<2;j++) acc[i][j] = (f32x4){0.f,0.f,0.f,0.f};

  // staging geometry: thread t handles 16B (4 fp32) at LDS flat index j*1024 + t*4 (j=0,1)
  //   row = j*16 + (t>>4), lds col = (t&15)*4, source col = lds col ^ ((row&3)*4)
  int srow = tid >> 4;                        // 0..15
  int scl  = (tid & 15) << 2;
  int ssc  = scl ^ ((srow & 3) << 2);         // (row+16)&3 == row&3, so same for j=1
  int sg0  = min(bx*32 + srow,      N_NODES-1);
  int sg1  = min(bx*32 + 16 + srow, N_NODES-1);
  const float* gp0 = x + (size_t)sg0*FIN + ssc;
  const float* gp1 = x + (size_t)sg1*FIN + ssc;
  char* lbase = smem + (wave << 10);          // wave-uniform; lane adds lane*16

#define STAGE_A(p, kt) do{                                                              \
    __builtin_amdgcn_global_load_lds((const __attribute__((address_space(1))) void*)(gp0 + (kt)), \
        (__attribute__((address_space(3))) void*)(lbase + (p)*8192), 16, 0, 0);         \
    __builtin_amdgcn_global_load_lds((const __attribute__((address_space(1))) void*)(gp1 + (kt)), \
        (__attribute__((address_space(3))) void*)(lbase + (p)*8192 + 4096), 16, 0, 0);  \
  }while(0)

  const ushort* wpB = Wtb + (size_t)quad*1024 + (size_t)(wave*32 + l15)*8;

  STAGE_A(0, 0);
  STAGE_A(1, 64);
  bf16x8 bcur[2][2];
  #pragma unroll
  for(int ks=0;ks<2;ks++)
    #pragma unroll
    for(int tn=0;tn<2;tn++)
      bcur[ks][tn] = *(const bf16x8*)(wpB + ks*4096 + tn*128);
  __builtin_amdgcn_sched_barrier(0);
  asm volatile("s_waitcnt vmcnt(0)" ::: "memory");
  __builtin_amdgcn_s_barrier();
  __builtin_amdgcn_sched_barrier(0);

  int cur = 0;
  #pragma unroll 1
  for(int kt=0; kt<FIN; kt+=64){
    bool hn = (kt + 64)  < FIN;
    bool h2 = (kt + 128) < FIN;

    if(h2){
      int nb = cur + 2; if(nb >= 3) nb -= 3;
      STAGE_A(nb, kt+128);
    }

    bf16x8 bnext[2][2];
    if(hn){
      #pragma unroll
      for(int ks=0;ks<2;ks++)
        #pragma unroll
        for(int tn=0;tn<2;tn++)
          bnext[ks][tn] = *(const bf16x8*)(wpB + (size_t)(kt+64)*128 + ks*4096 + tn*128);
    }

    bf16x8 af[2][2];
    #pragma unroll
    for(int tm=0;tm<2;tm++)
      #pragma unroll
      for(int ks=0;ks<2;ks++){
        int r  = tm*16 + l15;
        int cA = (ks*32 + quad*8) ^ ((r & 3) << 2);
        const float* fp = AsmF + cur*2048 + r*64;
        float4 fa = *(const float4*)(fp + cA);
        float4 fb = *(const float4*)(fp + (cA ^ 4));
        af[tm][ks] = cvt8(fa, fb);
      }

    #pragma unroll
    for(int ks=0;ks<2;ks++)
      #pragma unroll
      for(int tm=0;tm<2;tm++)
        #pragma unroll
        for(int tn=0;tn<2;tn++)
          acc[tm][tn] = __builtin_amdgcn_mfma_f32_16x16x32_bf16(af[tm][ks], bcur[ks][tn], acc[tm][tn], 0,0,0);

    if(hn){
      __builtin_amdgcn_sched_barrier(0);
      if(h2) asm volatile("s_waitcnt vmcnt(6)" ::: "memory");  // leave S_{t+2}(2)+B_{t+1}(4); S_{t+1} done
      else   asm volatile("s_waitcnt vmcnt(4)" ::: "memory");  // tail: leave B_{t+1}(4) only
      __builtin_amdgcn_s_barrier();
      __builtin_amdgcn_sched_barrier(0);
      #pragma unroll
      for(int ks=0;ks<2;ks++)
        #pragma unroll
        for(int tn=0;tn<2;tn++)
          bcur[ks][tn] = bnext[ks][tn];
    }
    cur = cur + 1; if(cur >= 3) cur -= 3;
  }

  // att weights for this wave's two heads (head = wave*2 + tn), channel = l15
  float wsv[2], wdv[2];
  #pragma unroll
  for(int tn=0;tn<2;tn++){
    int h = wave*2 + tn;
    wsv[tn] = as_w[h*16 + l15];
    wdv[tn] = ad_w[h*16 + l15];
  }

  #pragma unroll
  for(int tm=0;tm<2;tm++){
    #pragma unroll
    for(int r=0;r<4;r++){
      int row = bx*32 + tm*16 + quad*4 + r;
      bool ok = row < N_NODES;
      #pragma unroll
      for(int tn=0;tn<2;tn++){
        float v = acc[tm][tn][r];
        if(ok){
          int col = wave*32 + tn*16 + l15;
          h1b[(size_t)row*F1 + col] = f2bf(v);
        }
        float ss = v * wsv[tn];
        float dd = v * wdv[tn];
        #pragma unroll
        for(int m=8;m;m>>=1){ ss += __shfl_xor(ss, m); dd += __shfl_xor(dd, m); }
        if(ok && l15 == 0){
          int h = wave*2 + tn;
          a_src[(size_t)row*H1 + h] = ss;
          a_dst[(size_t)row*H1 + h] = dd;
        }
      }
    }
  }
#undef STAGE_A
}

// ---------------- layer-1 aggregation (bucket, in-loop w, 4-way MLP) + ELU -> bf16 g ----------------
// Round-3 verified form: one wave per node, 4 nodes/block.

__global__ __launch_bounds__(256) void k_agg1(const ushort* __restrict__ h1b, const float* __restrict__ a_src,
                                              const float* __restrict__ a_dst,
                                              const int* __restrict__ cnt, const ushort* __restrict__ bucket,
                                              const float* __restrict__ b1, ushort* __restrict__ gb){
  int wave = threadIdx.x >> 6, lane = threadIdx.x & 63;
  int n = blockIdx.x*4 + wave;
  if(n >= N_NODES) return;
  int hl = lane >> 3;
  float adv = a_dst[n*H1 + hl];
  int deg = min(cnt[n], BCAP);
  int sv = (int)bucket[(n << 6) + lane];  // one coalesced load; lanes >= deg unused
  const uint* h1u = (const uint*)h1b;     // lane covers channels 2*lane, 2*lane+1

  float ws0=0.f, ax0=0.f, ay0=0.f;
  float ws1=0.f, ax1=0.f, ay1=0.f;
  float ws2=0.f, ax2=0.f, ay2=0.f;
  float ws3=0.f, ax3=0.f, ay3=0.f;
  int j = 0;
  for(; j+3<deg; j+=4){
    int s0 = __shfl(sv, j),   s1 = __shfl(sv, j+1);
    int s2 = __shfl(sv, j+2), s3 = __shfl(sv, j+3);
    float e0 = a_src[s0*H1 + hl] + adv;
    float e1 = a_src[s1*H1 + hl] + adv;
    float e2 = a_src[s2*H1 + hl] + adv;
    float e3 = a_src[s3*H1 + hl] + adv;
    e0 = e0 > 0.f ? e0 : 0.2f*e0;  e1 = e1 > 0.f ? e1 : 0.2f*e1;
    e2 = e2 > 0.f ? e2 : 0.2f*e2;  e3 = e3 > 0.f ? e3 : 0.2f*e3;
    float w0=__expf(e0), w1=__expf(e1), w2=__expf(e2), w3=__expf(e3);
    uint u0 = h1u[(size_t)s0*64 + lane];
    uint u1 = h1u[(size_t)s1*64 + lane];
    uint u2 = h1u[(size_t)s2*64 + lane];
    uint u3 = h1u[(size_t)s3*64 + lane];
    ax0 += w0*bflo(u0); ay0 += w0*bfhi(u0); ws0 += w0;
    ax1 += w1*bflo(u1); ay1 += w1*bfhi(u1); ws1 += w1;
    ax2 += w2*bflo(u2); ay2 += w2*bfhi(u2); ws2 += w2;
    ax3 += w3*bflo(u3); ay3 += w3*bfhi(u3); ws3 += w3;
  }
  for(; j<deg; j++){
    int s0 = __shfl(sv, j);
    float e0 = a_src[s0*H1 + hl] + adv;
    e0 = e0 > 0.f ? e0 : 0.2f*e0;
    float w0 = __expf(e0);
    uint u0 = h1u[(size_t)s0*64 + lane];
    ax0 += w0*bflo(u0); ay0 += w0*bfhi(u0); ws0 += w0;
  }
  float wsum = (ws0+ws1)+(ws2+ws3);
  float inv = 1.f/(wsum + 1e-16f);
  int c0 = lane*2;
  float o0 = ((ax0+ax1)+(ax2+ax3))*inv + b1[c0];
  float o1 = ((ay0+ay1)+(ay2+ay3))*inv + b1[c0+1];
  o0 = o0 > 0.f ? o0 : expm1f(o0);
  o1 = o1 > 0.f ? o1 : expm1f(o1);
  uint up = (uint)f2bf(o0) | ((uint)f2bf(o1) << 16);
  ((uint*)gb)[(size_t)n*64 + lane] = up;
}

// ---------------- GEMM2 (bf16 MFMA): h2b = bf16(g @ W2)  (50000x128 @ 128x40, N padded to 48) ----------------

__global__ __launch_bounds__(256) void k_gemm2(const ushort* __restrict__ gb, const ushort* __restrict__ Wt2,
                                               const float* __restrict__ as_w, const float* __restrict__ ad_w,
                                               ushort* __restrict__ h2b,
                                               float* __restrict__ a_src, float* __restrict__ a_dst){
  int tid = threadIdx.x;
  int wave = tid >> 6, lane = tid & 63;
  int l15 = lane & 15, quad = lane >> 4;
  int row0 = blockIdx.x*64 + wave*16;
  int arow = min(row0 + l15, N_NODES-1);
  const ushort* ap = gb + (size_t)arow*F1 + quad*8;

  f32x4 acc[3];
  #pragma unroll
  for(int tn=0;tn<3;tn++) acc[tn] = (f32x4){0.f,0.f,0.f,0.f};

  #pragma unroll
  for(int ks=0;ks<4;ks++){
    bf16x8 af = *(const bf16x8*)(ap + ks*32);
    #pragma unroll
    for(int tn=0;tn<3;tn++){
      bf16x8 bf = *(const bf16x8*)(Wt2 + ((size_t)(ks*4+quad)*48 + tn*16 + l15)*8);
      acc[tn] = __builtin_amdgcn_mfma_f32_16x16x32_bf16(af, bf, acc[tn], 0,0,0);
    }
  }

  // att weights: col = tn*16 + l15, zero beyond F2
  float ws2v[3], wd2v[3];
  #pragma unroll
  for(int tn=0;tn<3;tn++){
    int col = tn*16 + l15;
    ws2v[tn] = (col < F2) ? as_w[col] : 0.f;
    wd2v[tn] = (col < F2) ? ad_w[col] : 0.f;
  }

  #pragma unroll
  for(int r=0;r<4;r++){
    int row = row0 + quad*4 + r;
    bool ok = row < N_NODES;
    float ss = 0.f, dd = 0.f;
    #pragma unroll
    for(int tn=0;tn<3;tn++){
      float v = acc[tn][r];
      int col = tn*16 + l15;
      if(ok && col < F2) h2b[(size_t)row*F2 + col] = f2bf(v);
      ss += v * ws2v[tn];
      dd += v * wd2v[tn];
    }
    #pragma unroll
    for(int m=8;m;m>>=1){ ss += __shfl_xor(ss, m); dd += __shfl_xor(dd, m); }
    if(ok && l15 == 0){
      a_src[row] = ss;
      a_dst[row] = dd;
    }
  }
}

// ---------------- layer-2 aggregation (bucket, in-loop w, 4-way MLP) + log_softmax ----------------

__global__ __launch_bounds__(256) void k_agg2(const ushort* __restrict__ h2b, const float* __restrict__ a_src,
                                              const float* __restrict__ a_dst,
                                              const int* __restrict__ cnt, const ushort* __restrict__ bucket,
                                              const float* __restrict__ b2, float* __restrict__ out){
  int wave = threadIdx.x >> 6, lane = threadIdx.x & 63;
  int n = blockIdx.x*4 + wave;
  if(n >= N_NODES) return;
  float adv = a_dst[n];
  int deg = min(cnt[n], BCAP);
  int sv = (int)bucket[(n << 6) + lane];
  int c = (lane < F2) ? lane : (F2-1);

  float ws0=0.f, ac0=0.f, ws1=0.f, ac1=0.f, ws2=0.f, ac2=0.f, ws3=0.f, ac3=0.f;
  int j = 0;
  for(; j+3<deg; j+=4){
    int s0 = __shfl(sv, j),   s1 = __shfl(sv, j+1);
    int s2 = __shfl(sv, j+2), s3 = __shfl(sv, j+3);
    float e0 = a_src[s0] + adv, e1 = a_src[s1] + adv;
    float e2 = a_src[s2] + adv, e3 = a_src[s3] + adv;
    e0 = e0 > 0.f ? e0 : 0.2f*e0;  e1 = e1 > 0.f ? e1 : 0.2f*e1;
    e2 = e2 > 0.f ? e2 : 0.2f*e2;  e3 = e3 > 0.f ? e3 : 0.2f*e3;
    float w0=__expf(e0), w1=__expf(e1), w2=__expf(e2), w3=__expf(e3);
    ac0 += w0*bf1(h2b[(size_t)s0*F2 + c]); ws0 += w0;
    ac1 += w1*bf1(h2b[(size_t)s1*F2 + c]); ws1 += w1;
    ac2 += w2*bf1(h2b[(size_t)s2*F2 + c]); ws2 += w2;
    ac3 += w3*bf1(h2b[(size_t)s3*F2 + c]); ws3 += w3;
  }
  for(; j<deg; j++){
    int s0 = __shfl(sv, j);
    float e0 = a_src[s0] + adv;
    e0 = e0 > 0.f ? e0 : 0.2f*e0;
    float w0 = __expf(e0);
    ac0 += w0*bf1(h2b[(size_t)s0*F2 + c]); ws0 += w0;
  }
  float v = ((ac0+ac1)+(ac2+ac3))/(((ws0+ws1)+(ws2+ws3)) + 1e-16f) + b2[c];
  float mv = (lane < F2) ? v : -INFINITY;
  #pragma unroll
  for(int off=32; off; off>>=1) mv = fmaxf(mv, __shfl_xor(mv, off));
  float ex = (lane < F2) ? __expf(v - mv) : 0.f;
  #pragma unroll
  for(int off=32; off; off>>=1) ex += __shfl_xor(ex, off);
  if(lane < F2) out[(size_t)n*F2 + lane] = v - mv - logf(ex);
}

// ---------------- launcher ----------------

extern "C" void kernel_launch(void* const* d_in, const int* in_sizes, int n_in,
                              void* d_out, int out_size, void* d_ws, size_t ws_size,
                              hipStream_t stream) {
  const float* x        = (const float*)d_in[0];
  const int*   eidx     = (const int*)d_in[1];
  const float* W1       = (const float*)d_in[2];
  const float* att_src1 = (const float*)d_in[3];
  const float* att_dst1 = (const float*)d_in[4];
  const float* b1       = (const float*)d_in[5];
  const float* W2       = (const float*)d_in[6];
  const float* att_src2 = (const float*)d_in[7];
  const float* att_dst2 = (const float*)d_in[8];
  const float* b2       = (const float*)d_in[9];
  float* out = (float*)d_out;

  const int* src = eidx;
  const int* dst = eidx + NE;

  // workspace layout
  ushort* h1b  = (ushort*)d_ws;                       // 6,400,000 ushort
  ushort* h2b  = h1b + 6400000;                       // 2,000,000
  ushort* gb   = h2b + 2000000;                       // 6,400,000
  ushort* Wtb  = gb + 6400000;                        // 65,536
  ushort* bucket = Wtb + 65536;                       // 3,200,000 ushort
  float* a_src1 = (float*)(bucket + 3200000);         // 400,000
  float* a_dst1 = a_src1 + 400000;                    // 400,000
  float* a_src2 = a_dst1 + 400000;                    // 50,000
  float* a_dst2 = a_src2 + 50000;                     // 50,000
  int* cnt      = (int*)(a_dst2 + 50000);             // 50,000 (+pad)
  int* binCursor= cnt + 50002;                        // 512
  uint* binbuf  = (uint*)(binCursor + 512);           // 391*3072 = 1,201,152
  ushort* Wt2   = (ushort*)(binbuf + (size_t)NBIN*BINCAP); // 6,144 ushort

  hipMemsetAsync(binCursor, 0, 512*sizeof(int), stream);

  // phase 1: binA + W-convert in one dispatch (independent roles)
  k_pro<<<174, 1024, 0, stream>>>(src, dst, binCursor, binbuf, W1, W2, Wtb, Wt2);

  // phase 2: binB + GEMM1 (3-deep counted-vmcnt DMA pipeline) in one dispatch
  k_g1b<<<NBIN + 1563, 256, 0, stream>>>(binCursor, binbuf, cnt, bucket,
                                         x, Wtb, att_src1, att_dst1, h1b, a_src1, a_dst1);

  // layer-1 aggregation
  k_agg1<<<(N_NODES+3)/4, 256, 0, stream>>>(h1b, a_src1, a_dst1, cnt, bucket, b1, gb);

  // layer 2 (att scores fused into GEMM epilogue)
  k_gemm2<<<(N_NODES+63)/64, 256, 0, stream>>>(gb, Wt2, att_src2, att_dst2, h2b, a_src2, a_dst2);
  k_agg2 <<<(N_NODES+3)/4, 256, 0, stream>>>(h2b, a_src2, a_dst2, cnt, bucket, b2, out);
}

// Round 13
// 278.158 us; speedup vs baseline: 1.0209x; 1.0209x over previous
//
#include <hip/hip_runtime.h>
#include <math.h>

#define N_NODES 50000
#define FIN 512
#define NE 800000
#define ETOT 850000   // NE + N_NODES self loops
#define F1 128        // H1*C1
#define H1 8
#define F2 40
#define BCAP 64       // bucket capacity per node (deg ~ 1+Poisson(16), P(>64) ~ 1e-20)
#define NBIN 391      // coarse bins of 128 nodes (ceil(50000/128))
#define BINCAP 3072   // per-bin edge capacity (mean 2176, sd 47 -> 19 sd margin)

typedef __attribute__((ext_vector_type(8))) short bf16x8;
typedef __attribute__((ext_vector_type(4))) float f32x4;

__device__ inline ushort f2bf(float f){
  union{float f; unsigned u;} v; v.f=f;
  return (ushort)((v.u + 0x8000u) >> 16);
}
__device__ inline float bflo(uint u){ union{uint a;float f;} v; v.a = u << 16;         return v.f; }
__device__ inline float bfhi(uint u){ union{uint a;float f;} v; v.a = u & 0xffff0000u; return v.f; }
__device__ inline float bf1(ushort u){ union{uint a;float f;} v; v.a = ((uint)u) << 16; return v.f; }

__device__ inline bf16x8 cvt8(float4 a, float4 b){
  union{ushort u[8]; bf16x8 v;} r;
  r.u[0]=f2bf(a.x); r.u[1]=f2bf(a.y); r.u[2]=f2bf(a.z); r.u[3]=f2bf(a.w);
  r.u[4]=f2bf(b.x); r.u[5]=f2bf(b.y); r.u[6]=f2bf(b.z); r.u[7]=f2bf(b.w);
  return r.v;
}

// ---------------- k_pro: role-split merge of binA (blocks 0..207) + W-convert (blocks 208..277) -------
// binA bins edges into 391 ranges of 128 nodes (LDS histogram, chunked writes).
// R12 change: 208 binA blocks x 4096 edges (was 104 x 8192) — the old grid used <half the CUs.

__global__ __launch_bounds__(1024) void k_pro(const int* __restrict__ src, const int* __restrict__ dst,
                                              int* __restrict__ binCursor, uint* __restrict__ binbuf,
                                              const float* __restrict__ W1, const float* __restrict__ W2,
                                              ushort* __restrict__ Wtb, ushort* __restrict__ Wt2){
  __shared__ int hist[512];
  __shared__ int base[512];
  int bx = blockIdx.x, t = threadIdx.x;

  if(bx < 208){
    if(t < 512) hist[t] = 0;
    __syncthreads();

    uint pk[4]; int bn[4];
    int i0 = bx*4096 + t;
    #pragma unroll
    for(int k=0;k<4;k++){
      int i = i0 + k*1024;
      int d = -1, s = 0;
      if(i < NE){ d = dst[i]; s = src[i]; }
      else if(i < ETOT){ d = i - NE; s = d; }
      if(d >= 0){
        bn[k] = d >> 7;
        pk[k] = ((uint)d << 16) | (uint)s;
        atomicAdd(&hist[bn[k]], 1);
      } else bn[k] = -1;
    }
    __syncthreads();
    if(t < 512){
      int h = hist[t];
      base[t] = (t < NBIN && h > 0) ? atomicAdd(&binCursor[t], h) : 0;
    }
    __syncthreads();
    if(t < 512) hist[t] = 0;   // reuse as local cursor
    __syncthreads();
    #pragma unroll
    for(int k=0;k<4;k++){
      if(bn[k] >= 0){
        int off = atomicAdd(&hist[bn[k]], 1);
        binbuf[(size_t)bn[k]*BINCAP + base[bn[k]] + off] = pk[k];
      }
    }
  } else {
    // ---- W1 + W2 convert to frag-blocked layouts ----
    int id = (bx - 208)*1024 + t;            // 0..71679
    if(id < 65536){
      int k = id >> 7, n = id & 127;
      Wtb[(size_t)(k>>3)*1024 + n*8 + (k&7)] = f2bf(W1[id]);
    } else {
      int id2 = id - 65536;
      if(id2 < 6144){
        int j = id2 & 7;
        int tt = id2 >> 3;         // 768
        int n = tt % 48;
        int t2 = tt / 48;          // 16
        int quad = t2 & 3, ks = t2 >> 2;
        int k = ks*32 + quad*8 + j;
        Wt2[id2] = (n < F2) ? f2bf(W2[k*F2 + n]) : (ushort)0;
      }
    }
  }
}

// ---------------- k_g1b: role-split at 256 threads — binB (blocks 0..390) + GEMM1 (blocks 391..1953) --
// GEMM1 reverted to the R7-VERIFIED form (best: 281.7us total, k_g1b ~58us): 32 rows/block,
// register-staged float4->cvt8->LDS, double-buffer, __syncthreads. Six alternative structures
// (1024t merge, 64-row, no-LDS, DMA-staged, counted-vmcnt 3-buf) all landed 58-82us — this is
// the stable local optimum for this tile/occupancy.

__global__ __launch_bounds__(256) void k_g1b(const int* __restrict__ binCursor, const uint* __restrict__ binbuf,
                                             int* __restrict__ cnt, ushort* __restrict__ bucket,
                                             const float* __restrict__ x, const ushort* __restrict__ Wtb,
                                             const float* __restrict__ as_w, const float* __restrict__ ad_w,
                                             ushort* __restrict__ h1b,
                                             float* __restrict__ a_src, float* __restrict__ a_dst){
  __shared__ __align__(16) char smem[17408];
  int bxg = blockIdx.x;

  if(bxg < NBIN){
    // ---- binB: per-128-node-bin LDS bucket build, coalesced writeout ----
    int* lcnt  = (int*)smem;                  // 128 ints
    ushort* lb = (ushort*)(smem + 512);       // [128][66] (pad 66: scatter banks spread by dl)
    int b = bxg, t = threadIdx.x;
    if(t < 128) lcnt[t] = 0;
    __syncthreads();
    int m = min(binCursor[b], BINCAP);
    const uint* p = binbuf + (size_t)b*BINCAP;
    for(int i=t; i<m; i+=256){
      uint pk = p[i];
      int dl = (pk >> 16) & 127;
      int pos = atomicAdd(&lcnt[dl], 1);
      if(pos < BCAP) lb[dl*66 + pos] = (ushort)(pk & 0xFFFF);
    }
    __syncthreads();
    int n0 = b << 7;
    int nrows = min(128, N_NODES - n0);
    if(t < nrows) cnt[n0 + t] = lcnt[t];
    const uint* s4 = (const uint*)(smem + 512);
    uint* d4 = (uint*)(bucket + ((size_t)n0 << 6));
    int total = nrows * 32;        // 32 dwords (64 ushorts) per row
    for(int i=t; i<total; i+=256){
      int r = i >> 5, c = i & 31;
      d4[i] = s4[r*33 + c];
    }
    return;
  }

  // ---- GEMM1 (bf16 MFMA) + fused att-score epilogue (R7 verified body) ----
  ushort* Asm = (ushort*)smem;                // [2][32][72]
  int tid = threadIdx.x;
  int bx  = bxg - NBIN;                       // 0..1562
  int wave = tid >> 6, lane = tid & 63;
  int l15 = lane & 15, quad = lane >> 4;

  f32x4 acc[2][2];
  #pragma unroll
  for(int i=0;i<2;i++)
    #pragma unroll
    for(int j=0;j<2;j++) acc[i][j] = (f32x4){0.f,0.f,0.f,0.f};

  int am  = tid >> 3;
  int ak8 = (tid & 7) << 3;
  int agr = bx*32 + am;
  int agrc = min(agr, N_NODES-1);
  const float* xrow = x + (size_t)agrc*FIN + ak8;

  {
    float4 a0 = *(const float4*)xrow;
    float4 a1 = *(const float4*)(xrow + 4);
    *(bf16x8*)&Asm[am*72 + ak8] = cvt8(a0, a1);
  }

  const ushort* wpB = Wtb + (size_t)quad*1024 + (size_t)(wave*32 + l15)*8;

  bf16x8 bcur[2][2];
  #pragma unroll
  for(int ks=0;ks<2;ks++)
    #pragma unroll
    for(int tn=0;tn<2;tn++)
      bcur[ks][tn] = *(const bf16x8*)(wpB + ks*4096 + tn*128);
  __syncthreads();

  for(int kt=0; kt<FIN; kt+=64){
    int cur = (kt >> 6) & 1;
    bool hn = (kt + 64) < FIN;

    float4 a0, a1;
    if(hn){
      a0 = *(const float4*)(xrow + kt + 64);
      a1 = *(const float4*)(xrow + kt + 68);
    }
    bf16x8 bnext[2][2];
    if(hn){
      #pragma unroll
      for(int ks=0;ks<2;ks++)
        #pragma unroll
        for(int tn=0;tn<2;tn++)
          bnext[ks][tn] = *(const bf16x8*)(wpB + (size_t)(kt+64)*128 + ks*4096 + tn*128);
    }

    bf16x8 af[2][2];
    #pragma unroll
    for(int tm=0;tm<2;tm++)
      #pragma unroll
      for(int ks=0;ks<2;ks++)
        af[tm][ks] = *(bf16x8*)&Asm[cur*2304 + (tm*16 + l15)*72 + ks*32 + quad*8];

    #pragma unroll
    for(int ks=0;ks<2;ks++)
      #pragma unroll
      for(int tm=0;tm<2;tm++)
        #pragma unroll
        for(int tn=0;tn<2;tn++)
          acc[tm][tn] = __builtin_amdgcn_mfma_f32_16x16x32_bf16(af[tm][ks], bcur[ks][tn], acc[tm][tn], 0,0,0);

    if(hn)
      *(bf16x8*)&Asm[(cur^1)*2304 + am*72 + ak8] = cvt8(a0, a1);
    __syncthreads();
    #pragma unroll
    for(int ks=0;ks<2;ks++)
      #pragma unroll
      for(int tn=0;tn<2;tn++)
        bcur[ks][tn] = bnext[ks][tn];
  }

  // att weights for this wave's two heads (head = wave*2 + tn), channel = l15
  float wsv[2], wdv[2];
  #pragma unroll
  for(int tn=0;tn<2;tn++){
    int h = wave*2 + tn;
    wsv[tn] = as_w[h*16 + l15];
    wdv[tn] = ad_w[h*16 + l15];
  }

  #pragma unroll
  for(int tm=0;tm<2;tm++){
    #pragma unroll
    for(int r=0;r<4;r++){
      int row = bx*32 + tm*16 + quad*4 + r;
      bool ok = row < N_NODES;
      #pragma unroll
      for(int tn=0;tn<2;tn++){
        float v = acc[tm][tn][r];
        if(ok){
          int col = wave*32 + tn*16 + l15;
          h1b[(size_t)row*F1 + col] = f2bf(v);
        }
        float ss = v * wsv[tn];
        float dd = v * wdv[tn];
        #pragma unroll
        for(int m=8;m;m>>=1){ ss += __shfl_xor(ss, m); dd += __shfl_xor(dd, m); }
        if(ok && l15 == 0){
          int h = wave*2 + tn;
          a_src[(size_t)row*H1 + h] = ss;
          a_dst[(size_t)row*H1 + h] = dd;
        }
      }
    }
  }
}

// ---------------- layer-1 aggregation (bucket, in-loop w, 4-way MLP) + ELU -> bf16 g ----------------
// Round-3 verified form: one wave per node, 4 nodes/block.

__global__ __launch_bounds__(256) void k_agg1(const ushort* __restrict__ h1b, const float* __restrict__ a_src,
                                              const float* __restrict__ a_dst,
                                              const int* __restrict__ cnt, const ushort* __restrict__ bucket,
                                              const float* __restrict__ b1, ushort* __restrict__ gb){
  int wave = threadIdx.x >> 6, lane = threadIdx.x & 63;
  int n = blockIdx.x*4 + wave;
  if(n >= N_NODES) return;
  int hl = lane >> 3;
  float adv = a_dst[n*H1 + hl];
  int deg = min(cnt[n], BCAP);
  int sv = (int)bucket[(n << 6) + lane];  // one coalesced load; lanes >= deg unused
  const uint* h1u = (const uint*)h1b;     // lane covers channels 2*lane, 2*lane+1

  float ws0=0.f, ax0=0.f, ay0=0.f;
  float ws1=0.f, ax1=0.f, ay1=0.f;
  float ws2=0.f, ax2=0.f, ay2=0.f;
  float ws3=0.f, ax3=0.f, ay3=0.f;
  int j = 0;
  for(; j+3<deg; j+=4){
    int s0 = __shfl(sv, j),   s1 = __shfl(sv, j+1);
    int s2 = __shfl(sv, j+2), s3 = __shfl(sv, j+3);
    float e0 = a_src[s0*H1 + hl] + adv;
    float e1 = a_src[s1*H1 + hl] + adv;
    float e2 = a_src[s2*H1 + hl] + adv;
    float e3 = a_src[s3*H1 + hl] + adv;
    e0 = e0 > 0.f ? e0 : 0.2f*e0;  e1 = e1 > 0.f ? e1 : 0.2f*e1;
    e2 = e2 > 0.f ? e2 : 0.2f*e2;  e3 = e3 > 0.f ? e3 : 0.2f*e3;
    float w0=__expf(e0), w1=__expf(e1), w2=__expf(e2), w3=__expf(e3);
    uint u0 = h1u[(size_t)s0*64 + lane];
    uint u1 = h1u[(size_t)s1*64 + lane];
    uint u2 = h1u[(size_t)s2*64 + lane];
    uint u3 = h1u[(size_t)s3*64 + lane];
    ax0 += w0*bflo(u0); ay0 += w0*bfhi(u0); ws0 += w0;
    ax1 += w1*bflo(u1); ay1 += w1*bfhi(u1); ws1 += w1;
    ax2 += w2*bflo(u2); ay2 += w2*bfhi(u2); ws2 += w2;
    ax3 += w3*bflo(u3); ay3 += w3*bfhi(u3); ws3 += w3;
  }
  for(; j<deg; j++){
    int s0 = __shfl(sv, j);
    float e0 = a_src[s0*H1 + hl] + adv;
    e0 = e0 > 0.f ? e0 : 0.2f*e0;
    float w0 = __expf(e0);
    uint u0 = h1u[(size_t)s0*64 + lane];
    ax0 += w0*bflo(u0); ay0 += w0*bfhi(u0); ws0 += w0;
  }
  float wsum = (ws0+ws1)+(ws2+ws3);
  float inv = 1.f/(wsum + 1e-16f);
  int c0 = lane*2;
  float o0 = ((ax0+ax1)+(ax2+ax3))*inv + b1[c0];
  float o1 = ((ay0+ay1)+(ay2+ay3))*inv + b1[c0+1];
  o0 = o0 > 0.f ? o0 : expm1f(o0);
  o1 = o1 > 0.f ? o1 : expm1f(o1);
  uint up = (uint)f2bf(o0) | ((uint)f2bf(o1) << 16);
  ((uint*)gb)[(size_t)n*64 + lane] = up;
}

// ---------------- GEMM2 (bf16 MFMA): h2b = bf16(g @ W2)  (50000x128 @ 128x40, N padded to 48) ----------------

__global__ __launch_bounds__(256) void k_gemm2(const ushort* __restrict__ gb, const ushort* __restrict__ Wt2,
                                               const float* __restrict__ as_w, const float* __restrict__ ad_w,
                                               ushort* __restrict__ h2b,
                                               float* __restrict__ a_src, float* __restrict__ a_dst){
  int tid = threadIdx.x;
  int wave = tid >> 6, lane = tid & 63;
  int l15 = lane & 15, quad = lane >> 4;
  int row0 = blockIdx.x*64 + wave*16;
  int arow = min(row0 + l15, N_NODES-1);
  const ushort* ap = gb + (size_t)arow*F1 + quad*8;

  f32x4 acc[3];
  #pragma unroll
  for(int tn=0;tn<3;tn++) acc[tn] = (f32x4){0.f,0.f,0.f,0.f};

  #pragma unroll
  for(int ks=0;ks<4;ks++){
    bf16x8 af = *(const bf16x8*)(ap + ks*32);
    #pragma unroll
    for(int tn=0;tn<3;tn++){
      bf16x8 bf = *(const bf16x8*)(Wt2 + ((size_t)(ks*4+quad)*48 + tn*16 + l15)*8);
      acc[tn] = __builtin_amdgcn_mfma_f32_16x16x32_bf16(af, bf, acc[tn], 0,0,0);
    }
  }

  // att weights: col = tn*16 + l15, zero beyond F2
  float ws2v[3], wd2v[3];
  #pragma unroll
  for(int tn=0;tn<3;tn++){
    int col = tn*16 + l15;
    ws2v[tn] = (col < F2) ? as_w[col] : 0.f;
    wd2v[tn] = (col < F2) ? ad_w[col] : 0.f;
  }

  #pragma unroll
  for(int r=0;r<4;r++){
    int row = row0 + quad*4 + r;
    bool ok = row < N_NODES;
    float ss = 0.f, dd = 0.f;
    #pragma unroll
    for(int tn=0;tn<3;tn++){
      float v = acc[tn][r];
      int col = tn*16 + l15;
      if(ok && col < F2) h2b[(size_t)row*F2 + col] = f2bf(v);
      ss += v * ws2v[tn];
      dd += v * wd2v[tn];
    }
    #pragma unroll
    for(int m=8;m;m>>=1){ ss += __shfl_xor(ss, m); dd += __shfl_xor(dd, m); }
    if(ok && l15 == 0){
      a_src[row] = ss;
      a_dst[row] = dd;
    }
  }
}

// ---------------- layer-2 aggregation (bucket, in-loop w, 4-way MLP) + log_softmax ----------------

__global__ __launch_bounds__(256) void k_agg2(const ushort* __restrict__ h2b, const float* __restrict__ a_src,
                                              const float* __restrict__ a_dst,
                                              const int* __restrict__ cnt, const ushort* __restrict__ bucket,
                                              const float* __restrict__ b2, float* __restrict__ out){
  int wave = threadIdx.x >> 6, lane = threadIdx.x & 63;
  int n = blockIdx.x*4 + wave;
  if(n >= N_NODES) return;
  float adv = a_dst[n];
  int deg = min(cnt[n], BCAP);
  int sv = (int)bucket[(n << 6) + lane];
  int c = (lane < F2) ? lane : (F2-1);

  float ws0=0.f, ac0=0.f, ws1=0.f, ac1=0.f, ws2=0.f, ac2=0.f, ws3=0.f, ac3=0.f;
  int j = 0;
  for(; j+3<deg; j+=4){
    int s0 = __shfl(sv, j),   s1 = __shfl(sv, j+1);
    int s2 = __shfl(sv, j+2), s3 = __shfl(sv, j+3);
    float e0 = a_src[s0] + adv, e1 = a_src[s1] + adv;
    float e2 = a_src[s2] + adv, e3 = a_src[s3] + adv;
    e0 = e0 > 0.f ? e0 : 0.2f*e0;  e1 = e1 > 0.f ? e1 : 0.2f*e1;
    e2 = e2 > 0.f ? e2 : 0.2f*e2;  e3 = e3 > 0.f ? e3 : 0.2f*e3;
    float w0=__expf(e0), w1=__expf(e1), w2=__expf(e2), w3=__expf(e3);
    ac0 += w0*bf1(h2b[(size_t)s0*F2 + c]); ws0 += w0;
    ac1 += w1*bf1(h2b[(size_t)s1*F2 + c]); ws1 += w1;
    ac2 += w2*bf1(h2b[(size_t)s2*F2 + c]); ws2 += w2;
    ac3 += w3*bf1(h2b[(size_t)s3*F2 + c]); ws3 += w3;
  }
  for(; j<deg; j++){
    int s0 = __shfl(sv, j);
    float e0 = a_src[s0] + adv;
    e0 = e0 > 0.f ? e0 : 0.2f*e0;
    float w0 = __expf(e0);
    ac0 += w0*bf1(h2b[(size_t)s0*F2 + c]); ws0 += w0;
  }
  float v = ((ac0+ac1)+(ac2+ac3))/(((ws0+ws1)+(ws2+ws3)) + 1e-16f) + b2[c];
  float mv = (lane < F2) ? v : -INFINITY;
  #pragma unroll
  for(int off=32; off; off>>=1) mv = fmaxf(mv, __shfl_xor(mv, off));
  float ex = (lane < F2) ? __expf(v - mv) : 0.f;
  #pragma unroll
  for(int off=32; off; off>>=1) ex += __shfl_xor(ex, off);
  if(lane < F2) out[(size_t)n*F2 + lane] = v - mv - logf(ex);
}

// ---------------- launcher ----------------

extern "C" void kernel_launch(void* const* d_in, const int* in_sizes, int n_in,
                              void* d_out, int out_size, void* d_ws, size_t ws_size,
                              hipStream_t stream) {
  const float* x        = (const float*)d_in[0];
  const int*   eidx     = (const int*)d_in[1];
  const float* W1       = (const float*)d_in[2];
  const float* att_src1 = (const float*)d_in[3];
  const float* att_dst1 = (const float*)d_in[4];
  const float* b1       = (const float*)d_in[5];
  const float* W2       = (const float*)d_in[6];
  const float* att_src2 = (const float*)d_in[7];
  const float* att_dst2 = (const float*)d_in[8];
  const float* b2       = (const float*)d_in[9];
  float* out = (float*)d_out;

  const int* src = eidx;
  const int* dst = eidx + NE;

  // workspace layout
  ushort* h1b  = (ushort*)d_ws;                       // 6,400,000 ushort
  ushort* h2b  = h1b + 6400000;                       // 2,000,000
  ushort* gb   = h2b + 2000000;                       // 6,400,000
  ushort* Wtb  = gb + 6400000;                        // 65,536
  ushort* bucket = Wtb + 65536;                       // 3,200,000 ushort
  float* a_src1 = (float*)(bucket + 3200000);         // 400,000
  float* a_dst1 = a_src1 + 400000;                    // 400,000
  float* a_src2 = a_dst1 + 400000;                    // 50,000
  float* a_dst2 = a_src2 + 50000;                     // 50,000
  int* cnt      = (int*)(a_dst2 + 50000);             // 50,000 (+pad)
  int* binCursor= cnt + 50002;                        // 512
  uint* binbuf  = (uint*)(binCursor + 512);           // 391*3072 = 1,201,152
  ushort* Wt2   = (ushort*)(binbuf + (size_t)NBIN*BINCAP); // 6,144 ushort

  hipMemsetAsync(binCursor, 0, 512*sizeof(int), stream);

  // phase 1: binA (208 blocks, full-machine) + W-convert in one dispatch
  k_pro<<<278, 1024, 0, stream>>>(src, dst, binCursor, binbuf, W1, W2, Wtb, Wt2);

  // phase 2: binB + GEMM1 (R7-verified form) in one dispatch, 256-thread blocks
  k_g1b<<<NBIN + 1563, 256, 0, stream>>>(binCursor, binbuf, cnt, bucket,
                                         x, Wtb, att_src1, att_dst1, h1b, a_src1, a_dst1);

  // layer-1 aggregation
  k_agg1<<<(N_NODES+3)/4, 256, 0, stream>>>(h1b, a_src1, a_dst1, cnt, bucket, b1, gb);

  // layer 2 (att scores fused into GEMM epilogue)
  k_gemm2<<<(N_NODES+63)/64, 256, 0, stream>>>(gb, Wt2, att_src2, att_dst2, h2b, a_src2, a_dst2);
  k_agg2 <<<(N_NODES+3)/4, 256, 0, stream>>>(h2b, a_src2, a_dst2, cnt, bucket, b2, out);
}